// Round 1
// baseline (250.609 us; speedup 1.0000x reference)
//
#include <hip/hip_runtime.h>
#include <math.h>

#define BB 2
#define NN 16384
#define MM 4096
#define CCH 16
#define KK 32
#define R2 0.01f
#define EPSV 1e-8f

__global__ __launch_bounds__(256) void grouper_fused(
    const float* __restrict__ xyz,      // B,N,3
    const float* __restrict__ new_xyz,  // B,M,3
    const float* __restrict__ feat,     // B,C,N
    const float* __restrict__ w0,       // 32,16
    const float* __restrict__ b0,       // 32
    const float* __restrict__ w1,       // 64,32
    const float* __restrict__ b1,       // 64
    const float* __restrict__ wxyz,     // 32,3
    const float* __restrict__ bxyz,     // 32
    float* __restrict__ out)            // [B*M*3] ++ [B,96,M]
{
    const int lane = threadIdx.x & 63;
    const int wid  = threadIdx.x >> 6;
    const int q    = (blockIdx.x << 2) + wid;   // 0..B*M-1
    const int b    = q >> 12;                   // q / 4096
    const int m    = q & (MM - 1);

    __shared__ int s_idx[4][KK];

    const float* xb = xyz + (size_t)b * NN * 3;
    const float qx = new_xyz[((size_t)b*MM + m)*3 + 0];
    const float qy = new_xyz[((size_t)b*MM + m)*3 + 1];
    const float qz = new_xyz[((size_t)b*MM + m)*3 + 2];

    // ---------- ball query: first K in-radius indices, ascending ----------
    int cnt = 0;
    for (int base = 0; base < NN; base += 64) {
        int i = base + lane;
        float px = xb[i*3+0];
        float py = xb[i*3+1];
        float pz = xb[i*3+2];
        float dx = px - qx, dy = py - qy, dz = pz - qz;
        float d2 = dx*dx + dy*dy + dz*dz;
        bool hit = d2 < R2;
        unsigned long long msk = __ballot(hit);
        int pos = cnt + __popcll(msk & ((1ull << lane) - 1ull));
        if (hit && pos < KK) s_idx[wid][pos] = i;
        cnt += __popcll(msk);
        if (cnt >= KK) break;
    }
    const int nfound = cnt < KK ? cnt : KK;

    // pad empty slots with first index (or 0 if no neighbor at all).
    // Same-wave lockstep: the ds_read for all lanes completes before ds_write.
    if (lane < KK) {
        int v = 0;
        if (nfound > 0) v = (lane < nfound) ? s_idx[wid][lane] : s_idx[wid][0];
        s_idx[wid][lane] = v;
    }

    const int k = lane & 31;
    const int h = lane >> 5;
    const int ik   = s_idx[wid][k];
    const int idx0 = s_idx[wid][0];

    // ---------- rel coords, dist, normalized weights ----------
    float px = xb[ik*3+0], py = xb[ik*3+1], pz = xb[ik*3+2];
    float rx = px - qx, ry = py - qy, rz = pz - qz;
    float dist = sqrtf(rx*rx + ry*ry + rz*rz);
    float recip = 1.0f / (dist + EPSV);
    // hit indices strictly ascending => only slot 0 and pads equal idx0
    float mult = (float)(1 + KK - nfound);
    float w = recip / ((ik == idx0) ? mult : 1.0f);
    float S = w;
    #pragma unroll
    for (int d = 1; d < 32; d <<= 1) S += __shfl_xor(S, d);
    const float wk = (nfound > 0) ? (w / S) : 0.0f;

    // ---------- gather features for column k ----------
    const float* fb = feat + (size_t)b * CCH * NN;
    float g[CCH];
    #pragma unroll
    for (int c = 0; c < CCH; ++c) g[c] = fb[c*NN + ik];

    // ---------- h0 = relu(W0 @ g + b0), all 32 channels per lane ----------
    float h0[32];
    #pragma unroll
    for (int o = 0; o < 32; ++o) {
        float acc = b0[o];
        #pragma unroll
        for (int c = 0; c < CCH; ++c) acc += w0[o*CCH + c] * g[c];
        h0[o] = fmaxf(acc, 0.0f);
    }

    float* out2 = out + (size_t)BB*MM*3 + (size_t)b*96*MM;

    // ---------- h1 = relu(W1 @ h0 + b1); feat_sum = sum_k wk*h1 ----------
    // half h owns output channels [h*32, h*32+32)
    const int chbase = h << 5;
    for (int oo = 0; oo < 32; ++oo) {
        const int O = chbase + oo;
        const float* wr = w1 + O*32;
        float acc = b1[O];
        #pragma unroll
        for (int o = 0; o < 32; ++o) acc += wr[o] * h0[o];
        float v = fmaxf(acc, 0.0f) * wk;
        #pragma unroll
        for (int d = 1; d < 32; d <<= 1) v += __shfl_xor(v, d);
        if (k == oo) out2[(32 + O)*MM + m] = v;
    }

    // ---------- xyz branch: hx = relu(Wxyz @ rel + bxyz); max over k ------
    // half h owns channels [h*16, h*16+16)
    for (int cc = 0; cc < 16; ++cc) {
        const int Cx = (h << 4) + cc;
        float v = bxyz[Cx] + wxyz[Cx*3+0]*rx + wxyz[Cx*3+1]*ry + wxyz[Cx*3+2]*rz;
        v = fmaxf(v, 0.0f);
        #pragma unroll
        for (int d = 1; d < 32; d <<= 1) v = fmaxf(v, __shfl_xor(v, d));
        if (k == cc) out2[Cx*MM + m] = v;
    }

    // ---------- new_xyz passthrough ----------
    if (lane == 0) {
        float* o0 = out + ((size_t)b*MM + m)*3;
        o0[0] = qx; o0[1] = qy; o0[2] = qz;
    }
}

extern "C" void kernel_launch(void* const* d_in, const int* in_sizes, int n_in,
                              void* d_out, int out_size, void* d_ws, size_t ws_size,
                              hipStream_t stream) {
    const float* xyz     = (const float*)d_in[0];
    const float* new_xyz = (const float*)d_in[1];
    const float* feat    = (const float*)d_in[2];
    const float* w0      = (const float*)d_in[3];
    const float* b0      = (const float*)d_in[4];
    const float* w1      = (const float*)d_in[5];
    const float* b1      = (const float*)d_in[6];
    const float* wxyz    = (const float*)d_in[7];
    const float* bxyz    = (const float*)d_in[8];
    float* out = (float*)d_out;

    dim3 grid((BB * MM) / 4), block(256);
    hipLaunchKernelGGL(grouper_fused, grid, block, 0, stream,
                       xyz, new_xyz, feat, w0, b0, w1, b1, wxyz, bxyz, out);
}

// Round 2
// 156.475 us; speedup vs baseline: 1.6016x; 1.6016x over previous
//
#include <hip/hip_runtime.h>
#include <math.h>

#define BB 2
#define NN 16384
#define MM 4096
#define CCH 16
#define KK 32
#define R2 0.01f
#define EPSV 1e-8f
// LDS row per neighbor k: [0..31]=h0, [32..34]=rel xyz, [35]=wk  (36 floats = 144B, 16B-aligned)
#define HSTRIDE 36

__global__ __launch_bounds__(256, 4) void grouper_fused(
    const float* __restrict__ xyz,      // B,N,3
    const float* __restrict__ new_xyz,  // B,M,3
    const float* __restrict__ feat,     // B,C,N
    const float* __restrict__ w0,       // 32,16
    const float* __restrict__ b0,       // 32
    const float* __restrict__ w1,       // 64,32
    const float* __restrict__ b1,       // 64
    const float* __restrict__ wxyz,     // 32,3
    const float* __restrict__ bxyz,     // 32
    float* __restrict__ out)            // [B*M*3] ++ [B,96,M]
{
    const int lane = threadIdx.x & 63;
    const int wid  = threadIdx.x >> 6;
    const int q    = (blockIdx.x << 2) + wid;   // 0..B*M-1
    const int b    = q >> 12;                   // q / 4096
    const int m    = q & (MM - 1);

    __shared__ int s_idx[4][KK];
    __shared__ __align__(16) float s_h0[4][KK * HSTRIDE];  // 4.5KB/wave

    const float* xb = xyz + (size_t)b * NN * 3;
    const float qx = new_xyz[((size_t)b*MM + m)*3 + 0];
    const float qy = new_xyz[((size_t)b*MM + m)*3 + 1];
    const float qz = new_xyz[((size_t)b*MM + m)*3 + 2];

    // ---------- ball query: first K in-radius indices, ascending ----------
    // 4 sub-chunks of 64 per iteration: 12 independent loads issue together,
    // one early-exit branch per 256 points.
    int cnt = 0;
    const unsigned long long below = (1ull << lane) - 1ull;
    for (int base = 0; base < NN; base += 256) {
        float d2[4];
        #pragma unroll
        for (int j = 0; j < 4; ++j) {
            int i = base + (j << 6) + lane;
            float px = xb[i*3+0];
            float py = xb[i*3+1];
            float pz = xb[i*3+2];
            float dx = px - qx, dy = py - qy, dz = pz - qz;
            d2[j] = dx*dx + dy*dy + dz*dz;
        }
        #pragma unroll
        for (int j = 0; j < 4; ++j) {
            bool hit = d2[j] < R2;
            unsigned long long msk = __ballot(hit);
            if (hit) {
                int pos = cnt + __popcll(msk & below);
                if (pos < KK) s_idx[wid][pos] = base + (j << 6) + lane;
            }
            cnt += __popcll(msk);
        }
        if (cnt >= KK) break;
    }
    const int nfound = cnt < KK ? cnt : KK;

    __builtin_amdgcn_wave_barrier();

    // pad empty slots with first index (or 0 if no neighbor at all)
    if (lane < KK) {
        int v = 0;
        if (nfound > 0) v = (lane < nfound) ? s_idx[wid][lane] : s_idx[wid][0];
        s_idx[wid][lane] = v;
    }

    __builtin_amdgcn_wave_barrier();

    const int k = lane & 31;
    const int h = lane >> 5;
    const int ik   = s_idx[wid][k];
    const int idx0 = s_idx[wid][0];

    // ---------- rel coords, dist, normalized weights (per k; dup across halves) --
    float px = xb[ik*3+0], py = xb[ik*3+1], pz = xb[ik*3+2];
    float rx = px - qx, ry = py - qy, rz = pz - qz;
    float dist = sqrtf(rx*rx + ry*ry + rz*rz);
    float recip = 1.0f / (dist + EPSV);
    // hit indices strictly ascending => only slot 0 and pads equal idx0
    float mult = (float)(1 + KK - nfound);
    float w = recip / ((ik == idx0) ? mult : 1.0f);
    float S = w;
    #pragma unroll
    for (int d = 1; d < 32; d <<= 1) S += __shfl_xor(S, d);
    const float wk = (nfound > 0) ? (w / S) : 0.0f;

    float* hrow_base = &s_h0[wid][0];
    if (h == 0) {
        float* r = hrow_base + k*HSTRIDE;
        r[32] = rx; r[33] = ry; r[34] = rz; r[35] = wk;
    }

    // ---------- gather features + h0 = relu(W0 g + b0) (w0 is wave-uniform) -----
    const float* fb = feat + (size_t)b * CCH * NN;
    float g[CCH];
    #pragma unroll
    for (int c = 0; c < CCH; ++c) g[c] = fb[c*NN + ik];

    float h0r[32];
    #pragma unroll
    for (int o = 0; o < 32; ++o) {
        float a0 = b0[o], a1 = 0.f, a2 = 0.f, a3 = 0.f;
        #pragma unroll
        for (int c = 0; c < CCH; c += 4) {
            a0 += w0[o*CCH + c + 0] * g[c + 0];
            a1 += w0[o*CCH + c + 1] * g[c + 1];
            a2 += w0[o*CCH + c + 2] * g[c + 2];
            a3 += w0[o*CCH + c + 3] * g[c + 3];
        }
        h0r[o] = fmaxf((a0 + a1) + (a2 + a3), 0.0f);
    }
    if (h == 0) {
        float4* dst = (float4*)(hrow_base + k*HSTRIDE);
        #pragma unroll
        for (int o = 0; o < 32; o += 4)
            dst[o >> 2] = make_float4(h0r[o], h0r[o+1], h0r[o+2], h0r[o+3]);
    }

    __builtin_amdgcn_wave_barrier();

    float* out2 = out + (size_t)BB*MM*3 + (size_t)b*96*MM;

    // ---------- layer 1 + weighted sum-pool: lane = output channel O (0..63) ----
    {
        const float* wr = w1 + lane*32;
        float w1r[32];
        #pragma unroll
        for (int o = 0; o < 32; o += 4) {
            float4 v4 = *(const float4*)(wr + o);
            w1r[o] = v4.x; w1r[o+1] = v4.y; w1r[o+2] = v4.z; w1r[o+3] = v4.w;
        }
        const float b1O = b1[lane];
        float acc_out = 0.0f;
        #pragma unroll 4
        for (int kk = 0; kk < KK; ++kk) {
            const float* hrow = hrow_base + kk*HSTRIDE;
            const float4* hv = (const float4*)hrow;   // broadcast reads
            float d0 = 0.f, d1 = 0.f, d2s = 0.f, d3 = 0.f;
            #pragma unroll
            for (int o = 0; o < 32; o += 4) {
                float4 hq = hv[o >> 2];
                d0 += w1r[o+0] * hq.x;
                d1 += w1r[o+1] * hq.y;
                d2s += w1r[o+2] * hq.z;
                d3 += w1r[o+3] * hq.w;
            }
            float dot = ((d0 + d1) + (d2s + d3)) + b1O;
            acc_out += hrow[35] * fmaxf(dot, 0.0f);
        }
        out2[(32 + lane)*MM + m] = acc_out;
    }

    // ---------- xyz branch: lane = channel c (halves split k), max-pool ---------
    {
        const int c = lane & 31;
        const float wx0 = wxyz[c*3+0], wx1 = wxyz[c*3+1], wx2 = wxyz[c*3+2];
        const float bc = bxyz[c];
        float v = 0.0f;   // relu output is >= 0, so 0 is the identity here
        #pragma unroll
        for (int kk = 0; kk < 16; ++kk) {
            const float* hr = hrow_base + ((h << 4) + kk)*HSTRIDE;
            float t = bc + wx0*hr[32] + wx1*hr[33] + wx2*hr[34];
            v = fmaxf(v, fmaxf(t, 0.0f));
        }
        v = fmaxf(v, __shfl_xor(v, 32));
        if (h == 0) out2[c*MM + m] = v;
    }

    // ---------- new_xyz passthrough ----------
    if (lane == 0) {
        float* o0 = out + ((size_t)b*MM + m)*3;
        o0[0] = qx; o0[1] = qy; o0[2] = qz;
    }
}

extern "C" void kernel_launch(void* const* d_in, const int* in_sizes, int n_in,
                              void* d_out, int out_size, void* d_ws, size_t ws_size,
                              hipStream_t stream) {
    const float* xyz     = (const float*)d_in[0];
    const float* new_xyz = (const float*)d_in[1];
    const float* feat    = (const float*)d_in[2];
    const float* w0      = (const float*)d_in[3];
    const float* b0      = (const float*)d_in[4];
    const float* w1      = (const float*)d_in[5];
    const float* b1      = (const float*)d_in[6];
    const float* wxyz    = (const float*)d_in[7];
    const float* bxyz    = (const float*)d_in[8];
    float* out = (float*)d_out;

    dim3 grid((BB * MM) / 4), block(256);
    hipLaunchKernelGGL(grouper_fused, grid, block, 0, stream,
                       xyz, new_xyz, feat, w0, b0, w1, b1, wxyz, bxyz, out);
}